// Round 3
// baseline (690.486 us; speedup 1.0000x reference)
//
#include <hip/hip_runtime.h>

// LocalSelfAttention2d: B=16, C=256, H=W=64, P=8, HEADS=8, D=32
// Round 2: fp32 baseline, rel-bias index FIXED (was sign-flipped:
//   reference bias[h,q,k] = position[h, ky-qy+8, kx-qx+8]).
//   Kernel F: per-(batch,window) fused qkv-projection + windowed attention,
//             writes attention output o (img layout) into d_out as scratch.
//   Kernel G: in-place 1x1 out-projection (+bias) on d_out.

#define SCALE 0.17677669529663687f  // 1/sqrt(32)

__global__ __launch_bounds__(512)
void fused_qkv_attn(const float* __restrict__ x,
                    const float* __restrict__ w_proj,
                    const float* __restrict__ position,
                    float* __restrict__ o_img) {
    __shared__ float Xw[256][64];    // x window, [c][p]
    __shared__ float QKV[192][68];   // [s*64 + hh*32 + d][p], pad 68 (16B-aligned rows)
    __shared__ float UB[8320];       // union: Wc[192][33] (6336 f) | Sc[128][65] (8320 f)

    float (*Wc)[33] = reinterpret_cast<float (*)[33]>(UB);

    const int tid = threadIdx.x;
    const int win = blockIdx.x;      // 0..63
    const int b   = blockIdx.y;      // 0..15
    const int wy = win >> 3, wx = win & 7;

    const float* xb = x + (size_t)b * 256 * 4096;

    // ---- stage x window: 256c x 64p, float4 along p
    #pragma unroll
    for (int i = 0; i < 8; ++i) {
        int idx = tid + i * 512;          // float4 index, 4096 total
        int c  = idx >> 4;
        int p4 = (idx & 15) << 2;
        int py = p4 >> 3, px = p4 & 7;    // p4 is 4-aligned: px in {0,4}
        const float* src = xb + (size_t)c * 4096 + (wy * 8 + py) * 64 + wx * 8 + px;
        *reinterpret_cast<float4*>(&Xw[c][p4]) = *reinterpret_cast<const float4*>(src);
    }
    __syncthreads();

    const int og = tid >> 4;   // 0..31 (6 output rows each)
    const int pg = tid & 15;   // 0..15 (4 pixels each)

    for (int hp = 0; hp < 4; ++hp) {   // head pairs: heads hp*2, hp*2+1
        // ======== QKV GEMM: [192 rows = s*64+hh*32+d] x [64 p], K=256 ========
        float acc[6][4];
        #pragma unroll
        for (int i = 0; i < 6; ++i)
            #pragma unroll
            for (int j = 0; j < 4; ++j) acc[i][j] = 0.f;

        for (int c0 = 0; c0 < 256; c0 += 32) {
            // stage Wc[192][32] (pad 33): row ol -> w_proj row s*256 + hp*64 + (ol&63)
            #pragma unroll
            for (int i = 0; i < 3; ++i) {
                int idx = tid + i * 512;   // 0..1535 float4s
                int ol  = idx >> 3;
                int c4  = (idx & 7) << 2;
                int s   = ol >> 6;
                int rem = ol & 63;         // hh*32 + d
                const float* src = w_proj + (size_t)(s * 256 + hp * 64 + rem) * 256 + c0 + c4;
                float4 v = *reinterpret_cast<const float4*>(src);
                Wc[ol][c4 + 0] = v.x; Wc[ol][c4 + 1] = v.y;
                Wc[ol][c4 + 2] = v.z; Wc[ol][c4 + 3] = v.w;
            }
            __syncthreads();
            #pragma unroll 8
            for (int cc = 0; cc < 32; ++cc) {
                float4 xv = *reinterpret_cast<const float4*>(&Xw[c0 + cc][pg << 2]);
                #pragma unroll
                for (int i = 0; i < 6; ++i) {
                    float w = Wc[og * 6 + i][cc];
                    acc[i][0] += w * xv.x; acc[i][1] += w * xv.y;
                    acc[i][2] += w * xv.z; acc[i][3] += w * xv.w;
                }
            }
            __syncthreads();
        }
        #pragma unroll
        for (int i = 0; i < 6; ++i) {
            float4 v = make_float4(acc[i][0], acc[i][1], acc[i][2], acc[i][3]);
            *reinterpret_cast<float4*>(&QKV[og * 6 + i][pg << 2]) = v;
        }
        __syncthreads();

        // ======== scores + bias + softmax (2 heads in parallel) ========
        {
            const int hh = tid >> 8;       // head within pair
            const int t  = tid & 255;
            const int qg = t >> 4;         // 4 q-rows each
            const int kg = t & 15;         // 4 k-cols each
            float sc[4][4];
            #pragma unroll
            for (int i = 0; i < 4; ++i)
                #pragma unroll
                for (int j = 0; j < 4; ++j) sc[i][j] = 0.f;

            for (int d = 0; d < 32; ++d) {
                float4 qv = *reinterpret_cast<const float4*>(&QKV[hh * 32 + d][qg << 2]);
                float4 kv = *reinterpret_cast<const float4*>(&QKV[64 + hh * 32 + d][kg << 2]);
                sc[0][0] += qv.x * kv.x; sc[0][1] += qv.x * kv.y; sc[0][2] += qv.x * kv.z; sc[0][3] += qv.x * kv.w;
                sc[1][0] += qv.y * kv.x; sc[1][1] += qv.y * kv.y; sc[1][2] += qv.y * kv.z; sc[1][3] += qv.y * kv.w;
                sc[2][0] += qv.z * kv.x; sc[2][1] += qv.z * kv.y; sc[2][2] += qv.z * kv.z; sc[2][3] += qv.z * kv.w;
                sc[3][0] += qv.w * kv.x; sc[3][1] += qv.w * kv.y; sc[3][2] += qv.w * kv.z; sc[3][3] += qv.w * kv.w;
            }
            const float* pos = position + (hp * 2 + hh) * 256;  // [16][16]
            #pragma unroll
            for (int i = 0; i < 4; ++i) {
                int q = (qg << 2) + i, qy = q >> 3, qx = q & 7;
                float mx = -1e30f;
                #pragma unroll
                for (int j = 0; j < 4; ++j) {
                    int k = (kg << 2) + j, ky = k >> 3, kx = k & 7;
                    // bias[h,q,k] = position[h, ky-qy+8, kx-qx+8]  (FIXED sign)
                    sc[i][j] = sc[i][j] * SCALE + pos[(ky - qy + 8) * 16 + (kx - qx + 8)];
                    mx = fmaxf(mx, sc[i][j]);
                }
                #pragma unroll
                for (int off = 1; off < 16; off <<= 1)
                    mx = fmaxf(mx, __shfl_xor(mx, off));
                float sum = 0.f;
                #pragma unroll
                for (int j = 0; j < 4; ++j) {
                    sc[i][j] = __expf(sc[i][j] - mx);
                    sum += sc[i][j];
                }
                #pragma unroll
                for (int off = 1; off < 16; off <<= 1)
                    sum += __shfl_xor(sum, off);
                float inv = 1.f / sum;
                #pragma unroll
                for (int j = 0; j < 4; ++j)
                    UB[(hh * 64 + q) * 65 + (kg << 2) + j] = sc[i][j] * inv;
            }
        }
        __syncthreads();

        // ======== PV + write o to d_out (img layout) ========
        {
            const int hh  = tid >> 8;
            const int t   = tid & 255;
            const int pg2 = t & 15;   // p = pg2*4 + i
            const int dg  = t >> 4;   // d = dg*2 + j
            float o2[4][2];
            #pragma unroll
            for (int i = 0; i < 4; ++i) { o2[i][0] = 0.f; o2[i][1] = 0.f; }
            for (int k = 0; k < 64; ++k) {
                float v0 = QKV[128 + hh * 32 + dg * 2 + 0][k];
                float v1 = QKV[128 + hh * 32 + dg * 2 + 1][k];
                #pragma unroll
                for (int i = 0; i < 4; ++i) {
                    float pv = UB[(hh * 64 + (pg2 << 2) + i) * 65 + k];
                    o2[i][0] += pv * v0;
                    o2[i][1] += pv * v1;
                }
            }
            int p4 = pg2 << 2;
            int py = p4 >> 3, px = p4 & 7;
            #pragma unroll
            for (int j = 0; j < 2; ++j) {
                int ch = (hp * 2 + hh) * 32 + dg * 2 + j;
                float* dst = o_img + (size_t)(b * 256 + ch) * 4096 + (wy * 8 + py) * 64 + wx * 8 + px;
                *reinterpret_cast<float4*>(dst) = make_float4(o2[0][j], o2[1][j], o2[2][j], o2[3][j]);
            }
        }
        __syncthreads();
    }
}

__global__ __launch_bounds__(512)
void out_proj(const float* __restrict__ w_out,
              const float* __restrict__ b_out,
              float* __restrict__ io) {
    __shared__ float Ot[256][64];    // snapshot of the o tile [c][px]
    __shared__ float Woc[256][33];   // w_out chunk [oc][32c] (pad 33)

    const int tid = threadIdx.x;
    const int y = blockIdx.x;        // image row
    const int b = blockIdx.y;
    float* base = io + (size_t)b * 256 * 4096 + y * 64;

    // snapshot tile BEFORE any write (in-place safety; per-block tiles disjoint)
    #pragma unroll
    for (int i = 0; i < 8; ++i) {
        int idx = tid + i * 512;      // float4 idx
        int c  = idx >> 4;
        int p4 = (idx & 15) << 2;
        *reinterpret_cast<float4*>(&Ot[c][p4]) =
            *reinterpret_cast<const float4*>(base + (size_t)c * 4096 + p4);
    }
    __syncthreads();

    const int og = tid >> 4;   // oc = og*8 + i
    const int pg = tid & 15;   // px = pg*4 + j
    float acc[8][4];
    #pragma unroll
    for (int i = 0; i < 8; ++i)
        #pragma unroll
        for (int j = 0; j < 4; ++j) acc[i][j] = 0.f;

    for (int c0 = 0; c0 < 256; c0 += 32) {
        #pragma unroll
        for (int i = 0; i < 4; ++i) {
            int idx = tid + i * 512;   // 0..2047 float4s
            int oc = idx >> 3;
            int c4 = (idx & 7) << 2;
            float4 v = *reinterpret_cast<const float4*>(w_out + (size_t)oc * 256 + c0 + c4);
            Woc[oc][c4 + 0] = v.x; Woc[oc][c4 + 1] = v.y;
            Woc[oc][c4 + 2] = v.z; Woc[oc][c4 + 3] = v.w;
        }
        __syncthreads();
        #pragma unroll 8
        for (int cc = 0; cc < 32; ++cc) {
            float4 xv = *reinterpret_cast<const float4*>(&Ot[c0 + cc][pg << 2]);
            #pragma unroll
            for (int i = 0; i < 8; ++i) {
                float w = Woc[og * 8 + i][cc];
                acc[i][0] += w * xv.x; acc[i][1] += w * xv.y;
                acc[i][2] += w * xv.z; acc[i][3] += w * xv.w;
            }
        }
        __syncthreads();
    }
    #pragma unroll
    for (int i = 0; i < 8; ++i) {
        int oc = og * 8 + i;
        float bb = b_out[oc];
        float4 v = make_float4(acc[i][0] + bb, acc[i][1] + bb, acc[i][2] + bb, acc[i][3] + bb);
        *reinterpret_cast<float4*>(base + (size_t)oc * 4096 + (pg << 2)) = v;
    }
}

extern "C" void kernel_launch(void* const* d_in, const int* in_sizes, int n_in,
                              void* d_out, int out_size, void* d_ws, size_t ws_size,
                              hipStream_t stream) {
    const float* x      = (const float*)d_in[0];
    const float* w_proj = (const float*)d_in[1];
    const float* pos    = (const float*)d_in[2];
    const float* w_out  = (const float*)d_in[3];
    const float* b_out  = (const float*)d_in[4];
    float* out = (float*)d_out;

    // F: qkv + attention -> o into d_out (fully overwrites d_out; deterministic)
    fused_qkv_attn<<<dim3(64, 16), 512, 0, stream>>>(x, w_proj, pos, out);
    // G: in-place out-projection + bias on d_out
    out_proj<<<dim3(64, 16), 512, 0, stream>>>(w_out, b_out, out);
}

// Round 4
// 203.262 us; speedup vs baseline: 3.3970x; 3.3970x over previous
//
#include <hip/hip_runtime.h>

// LocalSelfAttention2d  B=16,C=256,H=W=64,P=8,HEADS=8,D=32
// Round 4: single fused kernel, all GEMMs on f16 MFMA (fp32 accumulate).
//   block = (window, batch), 512 threads = 8 waves; wave w = head w in attn.
//   LDS: AWT [64p][256c] f16 XOR-swizzled  (x-window, later reused for O^T)
//        HB  per-head: Q[64][40] | K[64][40] | V_t[32][72]; P[64][64] overlays Q/K
//        POSL rel-bias f32, BOUT bias f32
//   MFMA frags (16x16x32): A: row=l&15, k=(l>>4)*8+v ; B: col=l&15, same k;
//   D: col=l&15, row=(l>>4)*4+reg  (m89-verified family layout).

typedef _Float16 f16x8 __attribute__((ext_vector_type(8)));
typedef float    f32x4 __attribute__((ext_vector_type(4)));

#define SCALE 0.17677669529663687f  // 1/sqrt(32)

__device__ __forceinline__ f16x8 pack8(float4 a, float4 b) {
    f16x8 r;
    r[0] = (_Float16)a.x; r[1] = (_Float16)a.y; r[2] = (_Float16)a.z; r[3] = (_Float16)a.w;
    r[4] = (_Float16)b.x; r[5] = (_Float16)b.y; r[6] = (_Float16)b.z; r[7] = (_Float16)b.w;
    return r;
}
__device__ __forceinline__ unsigned short f2hu(float f) {
    _Float16 h = (_Float16)f;
    return __builtin_bit_cast(unsigned short, h);
}

__global__ __launch_bounds__(512, 2)
void lsa_fused(const float* __restrict__ x, const float* __restrict__ w_proj,
               const float* __restrict__ position, const float* __restrict__ w_out,
               const float* __restrict__ b_out, float* __restrict__ out)
{
    __shared__ unsigned short AWT[16384];   // 32768 B  [p][c] swizzled: x-window, then O^T
    __shared__ unsigned short HB[59392];    // 118784 B  8 x (Q 2560 | K 2560 | V_t 2304)
    __shared__ float POSL[2048];            // 8192 B   position [8][16][16]
    __shared__ float BOUT[256];             // 1024 B

    const int tid = threadIdx.x;
    const int win = blockIdx.x, b = blockIdx.y;
    const int wy = win >> 3, wx = win & 7;
    const int w = tid >> 6, l = tid & 63, lr = l & 15, lg = l >> 4;

    // ---------------- phase 1: stage x window (transpose + fp16 + swizzle) ----------------
    {
        const float* xb = x + ((size_t)b * 256) * 4096 + (wy * 8) * 64 + wx * 8;
        #pragma unroll
        for (int i = 0; i < 8; ++i) {
            int idx = tid + i * 512;          // 4096 float4s
            int c = idx >> 4, p4 = (idx & 15) << 2;
            int py = p4 >> 3, px = p4 & 7;    // px in {0,4}
            float4 v = *reinterpret_cast<const float4*>(xb + (size_t)c * 4096 + py * 64 + px);
            float vv[4] = {v.x, v.y, v.z, v.w};
            #pragma unroll
            for (int j = 0; j < 4; ++j) {
                int p = p4 + j;
                AWT[p * 256 + (((c >> 3) ^ (p & 7)) << 3) + (c & 7)] = f2hu(vv[j]);
            }
        }
        float4 pv = reinterpret_cast<const float4*>(position)[tid];   // 2048 floats total
        *reinterpret_cast<float4*>(&POSL[tid * 4]) = pv;
        if (tid < 256) BOUT[tid] = b_out[tid];
    }
    __syncthreads();

    // ---------------- phase 2: QKV GEMM  M=768(rows of w_proj) N=64(p) K=256 ----------------
    f32x4 acc[6][4];
    {
        const f32x4 z = {0.f, 0.f, 0.f, 0.f};
        #pragma unroll
        for (int i = 0; i < 6; ++i)
            #pragma unroll
            for (int j = 0; j < 4; ++j) acc[i][j] = z;

        const int rowb = w * 96 + lr;
        for (int kt = 0; kt < 8; ++kt) {
            f16x8 af[6];
            #pragma unroll
            for (int mt = 0; mt < 6; ++mt) {
                const float* s0 = w_proj + (size_t)(rowb + mt * 16) * 256 + kt * 32 + lg * 8;
                af[mt] = pack8(*reinterpret_cast<const float4*>(s0),
                               *reinterpret_cast<const float4*>(s0 + 4));
            }
            f16x8 bfr[4];
            #pragma unroll
            for (int nt = 0; nt < 4; ++nt) {
                int p = nt * 16 + lr, k = kt * 32 + lg * 8;
                bfr[nt] = *reinterpret_cast<const f16x8*>(&AWT[p * 256 + (((k >> 3) ^ (p & 7)) << 3)]);
            }
            #pragma unroll
            for (int mt = 0; mt < 6; ++mt)
                #pragma unroll
                for (int nt = 0; nt < 4; ++nt)
                    acc[mt][nt] = __builtin_amdgcn_mfma_f32_16x16x32_f16(af[mt], bfr[nt], acc[mt][nt], 0, 0, 0);
        }
    }

    // ---------------- phase 3: scatter QKV into per-head LDS ----------------
    {
        #pragma unroll
        for (int mt = 0; mt < 6; ++mt) {
            int R0 = w * 96 + mt * 16 + lg * 4;       // rows R0..R0+3 (d contiguous, same head)
            int s = R0 >> 8, h = (R0 >> 5) & 7, d0 = R0 & 31;
            int hb = h * 7424;
            #pragma unroll
            for (int nt = 0; nt < 4; ++nt) {
                int p = nt * 16 + lr;
                if (s < 2) {
                    unsigned long long pk =
                        (unsigned long long)f2hu(acc[mt][nt][0]) |
                        ((unsigned long long)f2hu(acc[mt][nt][1]) << 16) |
                        ((unsigned long long)f2hu(acc[mt][nt][2]) << 32) |
                        ((unsigned long long)f2hu(acc[mt][nt][3]) << 48);
                    *reinterpret_cast<unsigned long long*>(&HB[hb + s * 2560 + p * 40 + d0]) = pk;
                } else {
                    #pragma unroll
                    for (int r = 0; r < 4; ++r)
                        HB[hb + 5120 + (d0 + r) * 72 + p] = f2hu(acc[mt][nt][r]);
                }
            }
        }
    }
    __syncthreads();

    // ---------------- phase 4: attention, wave w = head w ----------------
    {
        const int hb = w * 7424;
        f16x8 qf[4], kf[4];
        #pragma unroll
        for (int t = 0; t < 4; ++t) {
            qf[t] = *reinterpret_cast<const f16x8*>(&HB[hb + (t * 16 + lr) * 40 + lg * 8]);
            kf[t] = *reinterpret_cast<const f16x8*>(&HB[hb + 2560 + (t * 16 + lr) * 40 + lg * 8]);
        }
        f32x4 sc[4][4];
        {
            const f32x4 z = {0.f, 0.f, 0.f, 0.f};
            #pragma unroll
            for (int qt = 0; qt < 4; ++qt)
                #pragma unroll
                for (int kt = 0; kt < 4; ++kt)
                    sc[qt][kt] = __builtin_amdgcn_mfma_f32_16x16x32_f16(qf[qt], kf[kt], z, 0, 0, 0);
        }
        // bias + softmax; P -> LDS (overlays Q/K, regs already loaded)
        const float* ph = &POSL[w * 256];
        #pragma unroll
        for (int qt = 0; qt < 4; ++qt) {
            #pragma unroll
            for (int r = 0; r < 4; ++r) {
                int q = qt * 16 + lg * 4 + r, qy = q >> 3, qx = q & 7;
                float v[4], mx = -1e30f;
                #pragma unroll
                for (int kt = 0; kt < 4; ++kt) {
                    int k = kt * 16 + lr, ky = k >> 3, kx = k & 7;
                    float t = sc[qt][kt][r] * SCALE + ph[(ky - qy + 8) * 16 + (kx - qx + 8)];
                    v[kt] = t; mx = fmaxf(mx, t);
                }
                mx = fmaxf(mx, __shfl_xor(mx, 1)); mx = fmaxf(mx, __shfl_xor(mx, 2));
                mx = fmaxf(mx, __shfl_xor(mx, 4)); mx = fmaxf(mx, __shfl_xor(mx, 8));
                float sum = 0.f;
                #pragma unroll
                for (int kt = 0; kt < 4; ++kt) { v[kt] = __expf(v[kt] - mx); sum += v[kt]; }
                sum += __shfl_xor(sum, 1); sum += __shfl_xor(sum, 2);
                sum += __shfl_xor(sum, 4); sum += __shfl_xor(sum, 8);
                float inv = 1.f / sum;
                #pragma unroll
                for (int kt = 0; kt < 4; ++kt) {
                    int k = kt * 16 + lr;
                    HB[hb + q * 64 + (((k >> 3) ^ (q & 7)) << 3) + (k & 7)] = f2hu(v[kt] * inv);
                }
            }
        }
        // PV: O[64q][32d] = P[64x64] * V[64x32]
        f32x4 oacc[4][2];
        {
            const f32x4 z = {0.f, 0.f, 0.f, 0.f};
            #pragma unroll
            for (int qt = 0; qt < 4; ++qt) { oacc[qt][0] = z; oacc[qt][1] = z; }
        }
        #pragma unroll
        for (int ks = 0; ks < 2; ++ks) {
            f16x8 pf[4], vf[2];
            #pragma unroll
            for (int qt = 0; qt < 4; ++qt) {
                int q = qt * 16 + lr, kb = ks * 4 + lg;
                pf[qt] = *reinterpret_cast<const f16x8*>(&HB[hb + q * 64 + ((kb ^ (q & 7)) << 3)]);
            }
            #pragma unroll
            for (int dt = 0; dt < 2; ++dt) {
                int d = dt * 16 + lr;
                vf[dt] = *reinterpret_cast<const f16x8*>(&HB[hb + 5120 + d * 72 + ks * 32 + lg * 8]);
            }
            #pragma unroll
            for (int qt = 0; qt < 4; ++qt)
                #pragma unroll
                for (int dt = 0; dt < 2; ++dt)
                    oacc[qt][dt] = __builtin_amdgcn_mfma_f32_16x16x32_f16(pf[qt], vf[dt], oacc[qt][dt], 0, 0, 0);
        }
        // O^T into AWT (x-window is dead): O_t[p][c = head*32+d]
        #pragma unroll
        for (int qt = 0; qt < 4; ++qt)
            #pragma unroll
            for (int dt = 0; dt < 2; ++dt)
                #pragma unroll
                for (int r = 0; r < 4; ++r) {
                    int p = qt * 16 + lg * 4 + r;
                    int c = w * 32 + dt * 16 + lr;
                    AWT[p * 256 + (((c >> 3) ^ (p & 7)) << 3) + (c & 7)] = f2hu(oacc[qt][dt][r]);
                }
    }
    __syncthreads();

    // ---------------- phase 5: out-projection  M=256(oc) N=64(p) K=256(c) + bias ----------------
    {
        f32x4 oa[2][4];
        {
            const f32x4 z = {0.f, 0.f, 0.f, 0.f};
            #pragma unroll
            for (int mt = 0; mt < 2; ++mt)
                #pragma unroll
                for (int nt = 0; nt < 4; ++nt) oa[mt][nt] = z;
        }
        for (int kt = 0; kt < 8; ++kt) {
            f16x8 wf[2];
            #pragma unroll
            for (int mt = 0; mt < 2; ++mt) {
                const float* s0 = w_out + (size_t)(w * 32 + mt * 16 + lr) * 256 + kt * 32 + lg * 8;
                wf[mt] = pack8(*reinterpret_cast<const float4*>(s0),
                               *reinterpret_cast<const float4*>(s0 + 4));
            }
            f16x8 of[4];
            #pragma unroll
            for (int nt = 0; nt < 4; ++nt) {
                int p = nt * 16 + lr, k = kt * 32 + lg * 8;
                of[nt] = *reinterpret_cast<const f16x8*>(&AWT[p * 256 + (((k >> 3) ^ (p & 7)) << 3)]);
            }
            #pragma unroll
            for (int mt = 0; mt < 2; ++mt)
                #pragma unroll
                for (int nt = 0; nt < 4; ++nt)
                    oa[mt][nt] = __builtin_amdgcn_mfma_f32_16x16x32_f16(wf[mt], of[nt], oa[mt][nt], 0, 0, 0);
        }
        float* ob = out + ((size_t)b * 256) * 4096 + (wy * 8) * 64 + wx * 8;
        #pragma unroll
        for (int mt = 0; mt < 2; ++mt)
            #pragma unroll
            for (int nt = 0; nt < 4; ++nt)
                #pragma unroll
                for (int r = 0; r < 4; ++r) {
                    int oc = w * 32 + mt * 16 + lg * 4 + r;
                    int p = nt * 16 + lr, py = p >> 3, px = p & 7;
                    ob[(size_t)oc * 4096 + py * 64 + px] = oa[mt][nt][r] + BOUT[oc];
                }
    }
}

extern "C" void kernel_launch(void* const* d_in, const int* in_sizes, int n_in,
                              void* d_out, int out_size, void* d_ws, size_t ws_size,
                              hipStream_t stream) {
    const float* x      = (const float*)d_in[0];
    const float* w_proj = (const float*)d_in[1];
    const float* pos    = (const float*)d_in[2];
    const float* w_out  = (const float*)d_in[3];
    const float* b_out  = (const float*)d_in[4];
    float* out = (float*)d_out;

    lsa_fused<<<dim3(64, 16), 512, 0, stream>>>(x, w_proj, pos, w_out, b_out, out);
}

// Round 5
// 178.505 us; speedup vs baseline: 3.8682x; 1.1387x over previous
//
#include <hip/hip_runtime.h>

// LocalSelfAttention2d  B=16,C=256,H=W=64,P=8,HEADS=8,D=32
// Round 5: occupancy attack. 3 kernels:
//  K0 conv_w: w_proj/w_out -> fp16 in d_ws (removes per-block cvt storm).
//  K1 lsa_qkv_attn: block=(win,b,head-quad) [2048 blocks], 8 waves, LDS 79.9KB
//     -> 2 blocks/CU. QKV GEMM (A=w16 direct global f16, B=x-window LDS),
//     S^T=mfma(Kfrag,Qfrag), in-reg softmax (+bias gathered from global),
//     P half-buffered in LDS, PV, O -> d_ws as fp16 [bw][p][c].
//  K2 lsa_outproj: zero-LDS GEMM, A=wo16 global f16, B=O scratch global f16,
//     +bias, fp32 stores to d_out.
// MFMA 16x16x32_f16 layouts (R4 end-to-end verified):
//   A: row=l&15, k=(l>>4)*8+v ; B: col=l&15, same k ; D: col=l&15, row=(l>>4)*4+r.

typedef _Float16 f16x8 __attribute__((ext_vector_type(8)));
typedef _Float16 f16x4 __attribute__((ext_vector_type(4)));
typedef float    f32x4 __attribute__((ext_vector_type(4)));
typedef unsigned short u16;
typedef unsigned long long u64;

#define SCALE 0.17677669529663687f  // 1/sqrt(32)
#define AWT_S 268   // x-window [64 p][268 c]: b64-aligned rows, read banks 6m%32 distinct
#define QK_S  40    // Q/K [64 pix][40 d]: 80B rows (16B aligned), 2-way banks
#define VT_S  72    // V  [32 d][72 k]: 144B rows (16B aligned), 2-way banks
#define PB_S  40    // P-half [64 q][40 k]: 80B rows

__device__ __forceinline__ u16 f2hu(float f) {
    _Float16 h = (_Float16)f; return __builtin_bit_cast(u16, h);
}
__device__ __forceinline__ u64 pack4h(f32x4 v) {
    return (u64)f2hu(v[0]) | ((u64)f2hu(v[1]) << 16)
         | ((u64)f2hu(v[2]) << 32) | ((u64)f2hu(v[3]) << 48);
}
__device__ __forceinline__ f16x8 ld2x4(const u16* p) {
    f16x4 lo = *(const f16x4*)p;
    f16x4 hi = *(const f16x4*)(p + 4);
    return __builtin_shufflevector(lo, hi, 0, 1, 2, 3, 4, 5, 6, 7);
}

// ---------------- K0: weight fp32 -> fp16 ----------------
__global__ __launch_bounds__(512)
void conv_w(const float* __restrict__ wp, const float* __restrict__ wo,
            u16* __restrict__ w16, u16* __restrict__ wo16) {
    int idx = blockIdx.x * 512 + threadIdx.x;
    if (idx < 196608) w16[idx] = f2hu(wp[idx]);
    int j = idx - 196608;
    if (j >= 0 && j < 65536) wo16[j] = f2hu(wo[j]);
}

// ---------------- K1: QKV projection + windowed attention ----------------
__global__ __launch_bounds__(512, 4)
void lsa_qkv_attn(const float* __restrict__ x, const u16* __restrict__ w16,
                  const float* __restrict__ position, u16* __restrict__ Ows)
{
    __shared__ u16 U[39936];   // 79872 B total
    u16* AWT = U;                          // [64][268] = 17152 elems (phases 1-2)
    u16* Qb  = U;                          // [4][64][40] = 10240 elems (overlay, ph3+)
    u16* Kb  = U + 10240;                  // [4][64][40]
    u16* Vt  = U + 20480;                  // [4][32][72] = 9216
    u16* Pb  = U + 29696;                  // [4][64][40] = 10240 -> 39936

    const int tid = threadIdx.x;
    const int win = blockIdx.x, b = blockIdx.y, hq = blockIdx.z;
    const int wy = win >> 3, wx = win & 7;
    const int w = tid >> 6, m = tid & 15, lg = (tid >> 4) & 3;

    // ---- phase 1: stage x window -> AWT [p][c] fp16
    {
        const float* xb = x + ((size_t)b * 256) * 4096 + (wy * 8) * 64 + wx * 8;
        #pragma unroll
        for (int i = 0; i < 8; ++i) {
            int idx = tid + i * 512;              // 4096 float4s
            int c = idx >> 4, p4 = (idx & 15) << 2;
            int py = p4 >> 3, px = p4 & 7;
            float4 v = *(const float4*)(xb + (size_t)c * 4096 + py * 64 + px);
            AWT[(p4 + 0) * AWT_S + c] = f2hu(v.x);
            AWT[(p4 + 1) * AWT_S + c] = f2hu(v.y);
            AWT[(p4 + 2) * AWT_S + c] = f2hu(v.z);
            AWT[(p4 + 3) * AWT_S + c] = f2hu(v.w);
        }
    }
    __syncthreads();

    // ---- phase 2: QKV GEMM, wave w owns 3 row-tiles of the 384 local rows
    f32x4 acc[3][4];
    int isv[3], hhv[3], d0v[3], rowg[3];
    {
        const f32x4 z = {0.f, 0.f, 0.f, 0.f};
        #pragma unroll
        for (int i = 0; i < 3; ++i) {
            #pragma unroll
            for (int nt = 0; nt < 4; ++nt) acc[i][nt] = z;
            int lr0 = (3 * w + i) * 16;           // local row: i_s*128 + hh*32 + d
            isv[i] = lr0 >> 7; hhv[i] = (lr0 >> 5) & 3; d0v[i] = lr0 & 31;
            rowg[i] = isv[i] * 256 + (hq * 4 + hhv[i]) * 32 + d0v[i];
        }
        for (int kt = 0; kt < 8; ++kt) {
            f16x8 af[3];
            #pragma unroll
            for (int i = 0; i < 3; ++i)
                af[i] = *(const f16x8*)(w16 + (size_t)(rowg[i] + m) * 256 + kt * 32 + lg * 8);
            f16x8 bf[4];
            #pragma unroll
            for (int nt = 0; nt < 4; ++nt)
                bf[nt] = ld2x4(AWT + (nt * 16 + m) * AWT_S + kt * 32 + lg * 8);
            #pragma unroll
            for (int i = 0; i < 3; ++i)
                #pragma unroll
                for (int nt = 0; nt < 4; ++nt)
                    acc[i][nt] = __builtin_amdgcn_mfma_f32_16x16x32_f16(af[i], bf[nt], acc[i][nt], 0, 0, 0);
        }
    }
    __syncthreads();   // AWT reads done; Qb/Kb/Vt may overlay it now

    // ---- phase 3: scatter Q/K/V to per-head LDS (packed writes)
    {
        #pragma unroll
        for (int i = 0; i < 3; ++i) {
            int i_s = isv[i], hh = hhv[i], d0 = d0v[i];
            #pragma unroll
            for (int nt = 0; nt < 4; ++nt) {
                int pix = nt * 16 + m;
                if (i_s < 2) {
                    u16* base = (i_s == 0) ? Qb : Kb;
                    *(u64*)(base + hh * 64 * QK_S + pix * QK_S + d0 + lg * 4) = pack4h(acc[i][nt]);
                } else {
                    #pragma unroll
                    for (int r = 0; r < 4; ++r)
                        Vt[hh * 32 * VT_S + (d0 + lg * 4 + r) * VT_S + pix] = f2hu(acc[i][nt][r]);
                }
            }
        }
    }
    __syncthreads();

    // ---- phase 4: attention; 2 waves per head (wave = (hh, q-half))
    {
        const int hh = w >> 1, qh = w & 1;
        const u16* Qh = Qb + hh * 64 * QK_S;
        const u16* Kh = Kb + hh * 64 * QK_S;
        const u16* Vh = Vt + hh * 32 * VT_S;
        u16* Ph = Pb + hh * 64 * PB_S;
        const float* posh = position + (hq * 4 + hh) * 256;

        f16x8 kf[4], qf[2];
        #pragma unroll
        for (int kt = 0; kt < 4; ++kt)
            kf[kt] = *(const f16x8*)(Kh + (kt * 16 + m) * QK_S + lg * 8);
        #pragma unroll
        for (int qi = 0; qi < 2; ++qi)
            qf[qi] = *(const f16x8*)(Qh + ((2 * qh + qi) * 16 + m) * QK_S + lg * 8);

        const f32x4 z = {0.f, 0.f, 0.f, 0.f};
        f32x4 st[4][2];
        #pragma unroll
        for (int kt = 0; kt < 4; ++kt)
            #pragma unroll
            for (int qi = 0; qi < 2; ++qi)
                st[kt][qi] = __builtin_amdgcn_mfma_f32_16x16x32_f16(kf[kt], qf[qi], z, 0, 0, 0);
        // st[kt][qi]: lane holds S[q = (2qh+qi)*16 + m][k = kt*16 + lg*4 + r]

        float inv[2];
        #pragma unroll
        for (int qi = 0; qi < 2; ++qi) {
            int q = (2 * qh + qi) * 16 + m, qy = q >> 3, qx = q & 7;
            float mx = -1e30f;
            #pragma unroll
            for (int kt = 0; kt < 4; ++kt)
                #pragma unroll
                for (int r = 0; r < 4; ++r) {
                    int k = kt * 16 + lg * 4 + r, ky = k >> 3, kx = k & 7;
                    float t = st[kt][qi][r] * SCALE + posh[(ky - qy + 8) * 16 + (kx - qx + 8)];
                    st[kt][qi][r] = t;
                    mx = fmaxf(mx, t);
                }
            mx = fmaxf(mx, __shfl_xor(mx, 16));
            mx = fmaxf(mx, __shfl_xor(mx, 32));
            float sum = 0.f;
            #pragma unroll
            for (int kt = 0; kt < 4; ++kt)
                #pragma unroll
                for (int r = 0; r < 4; ++r) {
                    float e = __expf(st[kt][qi][r] - mx);
                    st[kt][qi][r] = e; sum += e;
                }
            sum += __shfl_xor(sum, 16);
            sum += __shfl_xor(sum, 32);
            inv[qi] = 1.f / sum;
        }

        f32x4 ot[2][2];
        ot[0][0] = z; ot[0][1] = z; ot[1][0] = z; ot[1][1] = z;
        #pragma unroll
        for (int ks = 0; ks < 2; ++ks) {
            // write P-half [q][k-local 0..31] (each wave touches only its own q rows)
            #pragma unroll
            for (int kh = 0; kh < 2; ++kh) {
                int kt = 2 * ks + kh;
                #pragma unroll
                for (int qi = 0; qi < 2; ++qi) {
                    f32x4 pv = st[kt][qi] * inv[qi];
                    *(u64*)(Ph + ((2 * qh + qi) * 16 + m) * PB_S + kh * 16 + lg * 4) = pack4h(pv);
                }
            }
            f16x8 pf[2], vf[2];
            #pragma unroll
            for (int qi = 0; qi < 2; ++qi)
                pf[qi] = *(const f16x8*)(Ph + ((2 * qh + qi) * 16 + m) * PB_S + lg * 8);
            #pragma unroll
            for (int dt = 0; dt < 2; ++dt)
                vf[dt] = *(const f16x8*)(Vh + (dt * 16 + m) * VT_S + ks * 32 + lg * 8);
            #pragma unroll
            for (int qi = 0; qi < 2; ++qi)
                #pragma unroll
                for (int dt = 0; dt < 2; ++dt)
                    ot[qi][dt] = __builtin_amdgcn_mfma_f32_16x16x32_f16(pf[qi], vf[dt], ot[qi][dt], 0, 0, 0);
        }

        // O -> Ows [bw][p=q][c], fp16. ot: lane: c-col = dt*16+m, q-row = lg*4+r
        const size_t obase = (size_t)(b * 64 + win) * 16384;
        #pragma unroll
        for (int qi = 0; qi < 2; ++qi)
            #pragma unroll
            for (int dt = 0; dt < 2; ++dt) {
                int c = (hq * 4 + hh) * 32 + dt * 16 + m;
                #pragma unroll
                for (int r = 0; r < 4; ++r) {
                    int q = (2 * qh + qi) * 16 + lg * 4 + r;
                    Ows[obase + q * 256 + c] = f2hu(ot[qi][dt][r]);
                }
            }
    }
}

// ---------------- K2: out-projection (zero LDS) ----------------
__global__ __launch_bounds__(512, 4)
void lsa_outproj(const u16* __restrict__ Ows, const u16* __restrict__ wo16,
                 const float* __restrict__ b_out, float* __restrict__ out)
{
    const int tid = threadIdx.x;
    const int win = blockIdx.x, b = blockIdx.y;
    const int wy = win >> 3, wx = win & 7;
    const int w = tid >> 6, m = tid & 15, lg = (tid >> 4) & 3;
    const u16* Ow = Ows + (size_t)(b * 64 + win) * 16384;   // [64 p][256 c]

    f32x4 oa[2][4];
    {
        const f32x4 z = {0.f, 0.f, 0.f, 0.f};
        #pragma unroll
        for (int mt = 0; mt < 2; ++mt)
            #pragma unroll
            for (int nt = 0; nt < 4; ++nt) oa[mt][nt] = z;
    }
    for (int kt = 0; kt < 8; ++kt) {
        f16x8 wf[2];
        #pragma unroll
        for (int mt = 0; mt < 2; ++mt)
            wf[mt] = *(const f16x8*)(wo16 + (size_t)(w * 32 + mt * 16 + m) * 256 + kt * 32 + lg * 8);
        f16x8 of[4];
        #pragma unroll
        for (int nt = 0; nt < 4; ++nt)
            of[nt] = *(const f16x8*)(Ow + (nt * 16 + m) * 256 + kt * 32 + lg * 8);
        #pragma unroll
        for (int mt = 0; mt < 2; ++mt)
            #pragma unroll
            for (int nt = 0; nt < 4; ++nt)
                oa[mt][nt] = __builtin_amdgcn_mfma_f32_16x16x32_f16(wf[mt], of[nt], oa[mt][nt], 0, 0, 0);
    }
    float* ob = out + ((size_t)b * 256) * 4096 + (wy * 8) * 64 + wx * 8;
    #pragma unroll
    for (int mt = 0; mt < 2; ++mt)
        #pragma unroll
        for (int nt = 0; nt < 4; ++nt) {
            int p = nt * 16 + m, py = p >> 3, px = p & 7;
            #pragma unroll
            for (int r = 0; r < 4; ++r) {
                int oc = w * 32 + mt * 16 + lg * 4 + r;
                ob[(size_t)oc * 4096 + py * 64 + px] = oa[mt][nt][r] + b_out[oc];
            }
        }
}

extern "C" void kernel_launch(void* const* d_in, const int* in_sizes, int n_in,
                              void* d_out, int out_size, void* d_ws, size_t ws_size,
                              hipStream_t stream) {
    const float* x      = (const float*)d_in[0];
    const float* w_proj = (const float*)d_in[1];
    const float* pos    = (const float*)d_in[2];
    const float* w_out  = (const float*)d_in[3];
    const float* b_out  = (const float*)d_in[4];
    float* out = (float*)d_out;

    // d_ws layout: [0, 32MB): O fp16 [b*win][p][c] ; then w16 (384KB) ; wo16 (128KB)
    u16* Ows  = (u16*)d_ws;
    u16* w16  = (u16*)((char*)d_ws + 33554432);
    u16* wo16 = (u16*)((char*)d_ws + 33947648);

    conv_w<<<512, 512, 0, stream>>>(w_proj, w_out, w16, wo16);
    lsa_qkv_attn<<<dim3(64, 16, 2), 512, 0, stream>>>(x, w16, pos, Ows);
    lsa_outproj<<<dim3(64, 16), 512, 0, stream>>>(Ows, wo16, b_out, out);
}